// Round 1
// baseline (2256.616 us; speedup 1.0000x reference)
//
#include <hip/hip_runtime.h>

#define DEV __device__ __forceinline__

constexpr int D  = 128;
constexpr int H  = 8;
constexpr int HD = 16;
constexpr float EPS_Z   = 1e-8f;
constexpr float LN_EPS  = 1e-5f;
constexpr float NEG     = 0.01f;
constexpr float INV_SQD = 0.25f;   // 1/sqrt(16)

// ---------------- bf16 storage helpers (for e fallback) ----------------
DEV unsigned short f2bf_bits(float f) {
  unsigned int u = __float_as_uint(f);
  unsigned int r = (u + 0x7FFFu + ((u >> 16) & 1u)) >> 16;
  return (unsigned short)r;
}
DEV float bf2f_bits(unsigned short s) { return __uint_as_float(((unsigned int)s) << 16); }
DEV float loadE(const float* p) { return *p; }
DEV float loadE(const unsigned short* p) { return bf2f_bits(*p); }

template<typename ET>
DEV void storeRow4(ET* C, size_t base, const float4& ov) {
  if (sizeof(ET) == 4) {
    *(float4*)((float*)C + base) = ov;
  } else {
    ushort4 s4;
    s4.x = f2bf_bits(ov.x); s4.y = f2bf_bits(ov.y);
    s4.z = f2bf_bits(ov.z); s4.w = f2bf_bits(ov.w);
    *(ushort4*)((unsigned short*)C + base) = s4;
  }
}

// ---------------- CSR build ----------------
__global__ void k_zero_ints(int* p, long n) {
  long i = (long)blockIdx.x * blockDim.x + threadIdx.x;
  long st = (long)gridDim.x * blockDim.x;
  for (; i < n; i += st) p[i] = 0;
}

__global__ void k_count(const int* __restrict__ dst, int* __restrict__ cnt, int E_) {
  int i = blockIdx.x * blockDim.x + threadIdx.x;
  if (i < E_) atomicAdd(&cnt[dst[i]], 1);
}

__global__ void k_scan_part(const int* __restrict__ cnt, int* __restrict__ bsum, int N_) {
  __shared__ int s[256];
  int i = blockIdx.x * 256 + threadIdx.x;
  s[threadIdx.x] = (i < N_) ? cnt[i] : 0;
  __syncthreads();
  for (int off = 128; off > 0; off >>= 1) {
    if (threadIdx.x < off) s[threadIdx.x] += s[threadIdx.x + off];
    __syncthreads();
  }
  if (threadIdx.x == 0) bsum[blockIdx.x] = s[0];
}

__global__ void k_scan_mid(int* bsum, int nb) {
  if (threadIdx.x == 0 && blockIdx.x == 0) {
    int run = 0;
    for (int i = 0; i < nb; ++i) { int v = bsum[i]; bsum[i] = run; run += v; }
  }
}

__global__ void k_scan_fin(const int* __restrict__ cnt, const int* __restrict__ bsum,
                           int* __restrict__ offs, int N_, int E_) {
  __shared__ int s[256];
  int i = blockIdx.x * 256 + threadIdx.x;
  int v = (i < N_) ? cnt[i] : 0;
  s[threadIdx.x] = v;
  __syncthreads();
  for (int off = 1; off < 256; off <<= 1) {
    int y = (threadIdx.x >= off) ? s[threadIdx.x - off] : 0;
    __syncthreads();
    s[threadIdx.x] += y;
    __syncthreads();
  }
  if (i < N_) offs[i] = bsum[blockIdx.x] + s[threadIdx.x] - v;  // exclusive
  if (blockIdx.x == 0 && threadIdx.x == 0) offs[N_] = E_;
}

__global__ void k_scatter(const int* __restrict__ dst, const int* __restrict__ offs,
                          int* __restrict__ cursor, int* __restrict__ eids, int E_) {
  int i = blockIdx.x * blockDim.x + threadIdx.x;
  if (i < E_) {
    int dn = dst[i];
    int pos = offs[dn] + atomicAdd(&cursor[dn], 1);
    eids[pos] = i;
  }
}

// ---------------- GEMM core: C[M,128] = A[M,128] @ W[128,128] + b ----------------
// 256 threads, 64-row tile. a_s holds full A tile; w_s holds 32-row W chunk.
// thread (tc = t&31, tr = t>>5) owns rows tr*8..+7, cols tc*4..+3.
// EPI==1: additionally keep e tile in LDS and compute exp(q[dst].(k[src]+e)).
template<int EPI, typename ET>
DEV void gemm_body(const float* __restrict__ A, const float* __restrict__ W,
                   const float* __restrict__ bias, ET* __restrict__ C, int M,
                   const int* __restrict__ src, const int* __restrict__ dst,
                   const float* __restrict__ qm, const float* __restrict__ km,
                   float* __restrict__ escore,
                   float (&a_s)[64][D], float (&w_s)[32][D]) {
  const int t = threadIdx.x;
  const int row0 = blockIdx.x * 64;
#pragma unroll
  for (int i = 0; i < 8; ++i) {
    int f = t + i * 256;
    int row = f >> 5, c4 = f & 31;
    float4 v4 = make_float4(0.f, 0.f, 0.f, 0.f);
    if (row0 + row < M) v4 = *(const float4*)(A + (size_t)(row0 + row) * D + c4 * 4);
    *(float4*)(&a_s[row][c4 * 4]) = v4;
  }
  const int tc = t & 31, tr = t >> 5;
  float acc[8][4];
#pragma unroll
  for (int i = 0; i < 8; ++i)
#pragma unroll
    for (int j = 0; j < 4; ++j) acc[i][j] = 0.f;

  for (int k0 = 0; k0 < D; k0 += 32) {
    __syncthreads();
#pragma unroll
    for (int i = 0; i < 4; ++i) {
      int f = t + i * 256;
      int r = f >> 5, c4 = f & 31;
      *(float4*)(&w_s[r][c4 * 4]) = *(const float4*)(W + (size_t)(k0 + r) * D + c4 * 4);
    }
    __syncthreads();
#pragma unroll
    for (int kk = 0; kk < 32; kk += 4) {
      float4 wv0 = *(float4*)(&w_s[kk + 0][tc * 4]);
      float4 wv1 = *(float4*)(&w_s[kk + 1][tc * 4]);
      float4 wv2 = *(float4*)(&w_s[kk + 2][tc * 4]);
      float4 wv3 = *(float4*)(&w_s[kk + 3][tc * 4]);
#pragma unroll
      for (int i = 0; i < 8; ++i) {
        float4 av = *(float4*)(&a_s[tr * 8 + i][k0 + kk]);
        acc[i][0] += av.x * wv0.x + av.y * wv1.x + av.z * wv2.x + av.w * wv3.x;
        acc[i][1] += av.x * wv0.y + av.y * wv1.y + av.z * wv2.y + av.w * wv3.y;
        acc[i][2] += av.x * wv0.z + av.y * wv1.z + av.z * wv2.z + av.w * wv3.z;
        acc[i][3] += av.x * wv0.w + av.y * wv1.w + av.z * wv2.w + av.w * wv3.w;
      }
    }
  }
  float4 bv = *(const float4*)(bias + tc * 4);
  if (EPI == 0) {
#pragma unroll
    for (int i = 0; i < 8; ++i) {
      int row = tr * 8 + i;
      if (row0 + row < M) {
        float4 ov = make_float4(acc[i][0] + bv.x, acc[i][1] + bv.y,
                                acc[i][2] + bv.z, acc[i][3] + bv.w);
        *(float4*)((float*)C + (size_t)(row0 + row) * D + tc * 4) = ov;
      }
    }
  } else {
    __syncthreads();  // done reading a_s; reuse it for e tile
#pragma unroll
    for (int i = 0; i < 8; ++i) {
      int row = tr * 8 + i;
      float4 ov = make_float4(acc[i][0] + bv.x, acc[i][1] + bv.y,
                              acc[i][2] + bv.z, acc[i][3] + bv.w);
      *(float4*)(&a_s[row][tc * 4]) = ov;
      if (row0 + row < M) storeRow4(C, (size_t)(row0 + row) * D + tc * 4, ov);
    }
    __syncthreads();
    // scores: 512 (row,h) pairs, 2 per thread
#pragma unroll
    for (int pp = 0; pp < 2; ++pp) {
      int p = t + pp * 256;
      int row = p >> 3, h = p & 7;
      int grow = row0 + row;
      if (grow < M) {
        int s_ = src[grow], d_ = dst[grow];
        const float* qp = qm + (size_t)d_ * D + h * HD;
        const float* kp = km + (size_t)s_ * D + h * HD;
        float sc = 0.f;
#pragma unroll
        for (int i2 = 0; i2 < 4; ++i2) {
          float4 qv = *(const float4*)(qp + i2 * 4);
          float4 kv = *(const float4*)(kp + i2 * 4);
          float4 ev = *(float4*)(&a_s[row][h * HD + i2 * 4]);
          sc += qv.x * (kv.x + ev.x) + qv.y * (kv.y + ev.y) +
                qv.z * (kv.z + ev.z) + qv.w * (kv.w + ev.w);
        }
        escore[(size_t)grow * H + h] = expf(sc);
      }
    }
  }
}

struct PtrQuad { const float* W[4]; const float* b[4]; float* C[4]; };

__global__ __launch_bounds__(256)
void k_nodeproj(const float* __restrict__ x, PtrQuad pq, int M) {
  __shared__ float a_s[64][D];
  __shared__ float w_s[32][D];
  int wi = blockIdx.y;
  gemm_body<0, float>(x, pq.W[wi], pq.b[wi], pq.C[wi], M,
                      nullptr, nullptr, nullptr, nullptr, nullptr, a_s, w_s);
}

template<typename ET>
__global__ __launch_bounds__(256)
void k_gemm_edge(const float* __restrict__ y, const float* __restrict__ W,
                 const float* __restrict__ b, ET* __restrict__ C, int M,
                 const int* __restrict__ src, const int* __restrict__ dst,
                 const float* __restrict__ q, const float* __restrict__ k,
                 float* __restrict__ esc) {
  __shared__ float a_s[64][D];
  __shared__ float w_s[32][D];
  gemm_body<1, ET>(y, W, b, C, M, src, dst, q, k, esc, a_s, w_s);
}

// ---------------- gather: z, o, norm_escore per destination node ----------------
template<typename ET>
__global__ __launch_bounds__(128)
void k_gather(const int* __restrict__ eids_all, const int* __restrict__ offs,
              const int* __restrict__ src, const float* __restrict__ vmat,
              const ET* __restrict__ emat, const float* __restrict__ escore,
              float* __restrict__ o, float* __restrict__ out_ns) {
  int nid = blockIdx.x;
  int t = threadIdx.x;          // 0..127 ; h = t>>4, dim = t&15
  int h = t >> 4;
  int beg = offs[nid], end = offs[nid + 1];
  __shared__ int eids[128];
  __shared__ int srcs[128];
  float z0 = 0.f, z1 = 0.f;
  for (int c0 = beg; c0 < end; c0 += 128) {
    int cnt = min(128, end - c0);
    __syncthreads();
    if (t < cnt) eids[t] = eids_all[c0 + t];
    __syncthreads();
    int j = 0;
    for (; j + 1 < cnt; j += 2) {
      z0 += escore[(size_t)eids[j] * H + h];
      z1 += escore[(size_t)eids[j + 1] * H + h];
    }
    if (j < cnt) z0 += escore[(size_t)eids[j] * H + h];
  }
  float inv = INV_SQD / (EPS_Z + (z0 + z1));
  float acc0 = 0.f, acc1 = 0.f;
  for (int c0 = beg; c0 < end; c0 += 128) {
    int cnt = min(128, end - c0);
    __syncthreads();
    if (t < cnt) { int e_ = eids_all[c0 + t]; eids[t] = e_; srcs[t] = src[e_]; }
    __syncthreads();
    int j = 0;
    for (; j + 1 < cnt; j += 2) {
      int e0 = eids[j], e1 = eids[j + 1];
      float es0 = escore[(size_t)e0 * H + h];
      float es1 = escore[(size_t)e1 * H + h];
      float ev0 = loadE(emat + (size_t)e0 * D + t);
      float ev1 = loadE(emat + (size_t)e1 * D + t);
      float vv0 = vmat[(size_t)srcs[j] * D + t];
      float vv1 = vmat[(size_t)srcs[j + 1] * D + t];
      float ns0 = es0 * inv, ns1 = es1 * inv;
      if ((t & 15) == 0) {
        out_ns[(size_t)e0 * H + h] = ns0;
        out_ns[(size_t)e1 * H + h] = ns1;
      }
      acc0 += ns0 * (vv0 + ev0);
      acc1 += ns1 * (vv1 + ev1);
    }
    if (j < cnt) {
      int e0 = eids[j];
      float es0 = escore[(size_t)e0 * H + h];
      float ev0 = loadE(emat + (size_t)e0 * D + t);
      float vv0 = vmat[(size_t)srcs[j] * D + t];
      float ns0 = es0 * inv;
      if ((t & 15) == 0) out_ns[(size_t)e0 * H + h] = ns0;
      acc0 += ns0 * (vv0 + ev0);
    }
  }
  o[(size_t)nid * D + t] = acc0 + acc1;
}

// ---------------- gating GEMM + sigmoid + mix + LayerNorm + leaky ----------------
__global__ __launch_bounds__(256)
void k_final(const float* __restrict__ o, const float* __restrict__ r,
             const float* __restrict__ Wg, const float* __restrict__ bg,
             const float* __restrict__ lng, const float* __restrict__ lnb,
             float* __restrict__ xout, int M) {
  __shared__ float o_s[64][D];
  __shared__ float r_s[64][D];
  __shared__ float w_s[32][D];
  int t = threadIdx.x;
  int row0 = blockIdx.x * 64;
#pragma unroll
  for (int i = 0; i < 8; ++i) {
    int f = t + i * 256;
    int row = f >> 5, c4 = f & 31;
    float4 ov = make_float4(0.f, 0.f, 0.f, 0.f), rv = ov;
    if (row0 + row < M) {
      ov = *(const float4*)(o + (size_t)(row0 + row) * D + c4 * 4);
      rv = *(const float4*)(r + (size_t)(row0 + row) * D + c4 * 4);
    }
    *(float4*)(&o_s[row][c4 * 4]) = ov;
    *(float4*)(&r_s[row][c4 * 4]) = rv;
  }
  int tc = t & 31, tr = t >> 5;
  float acc[8][4] = {};
  for (int k0 = 0; k0 < 3 * D; k0 += 32) {
    int reg = k0 >> 7;       // 0: o, 1: r, 2: o-r
    int kb = k0 & 127;
    __syncthreads();
#pragma unroll
    for (int i = 0; i < 4; ++i) {
      int f = t + i * 256;
      int rr = f >> 5, c4 = f & 31;
      *(float4*)(&w_s[rr][c4 * 4]) = *(const float4*)(Wg + (size_t)(k0 + rr) * D + c4 * 4);
    }
    __syncthreads();
#pragma unroll
    for (int kk = 0; kk < 32; kk += 4) {
      float4 wv0 = *(float4*)(&w_s[kk + 0][tc * 4]);
      float4 wv1 = *(float4*)(&w_s[kk + 1][tc * 4]);
      float4 wv2 = *(float4*)(&w_s[kk + 2][tc * 4]);
      float4 wv3 = *(float4*)(&w_s[kk + 3][tc * 4]);
#pragma unroll
      for (int i = 0; i < 8; ++i) {
        int row = tr * 8 + i;
        float4 o4 = *(float4*)(&o_s[row][kb + kk]);
        float4 av;
        if (reg == 0) av = o4;
        else {
          float4 r4 = *(float4*)(&r_s[row][kb + kk]);
          if (reg == 1) av = r4;
          else av = make_float4(o4.x - r4.x, o4.y - r4.y, o4.z - r4.z, o4.w - r4.w);
        }
        acc[i][0] += av.x * wv0.x + av.y * wv1.x + av.z * wv2.x + av.w * wv3.x;
        acc[i][1] += av.x * wv0.y + av.y * wv1.y + av.z * wv2.y + av.w * wv3.y;
        acc[i][2] += av.x * wv0.z + av.y * wv1.z + av.z * wv2.z + av.w * wv3.z;
        acc[i][3] += av.x * wv0.w + av.y * wv1.w + av.z * wv2.w + av.w * wv3.w;
      }
    }
  }
  float4 bgv = *(const float4*)(bg + tc * 4);
  float hm[8][4];
#pragma unroll
  for (int i = 0; i < 8; ++i) {
    int row = tr * 8 + i;
    float bb0 = 1.f / (1.f + expf(-(acc[i][0] + bgv.x)));
    float bb1 = 1.f / (1.f + expf(-(acc[i][1] + bgv.y)));
    float bb2 = 1.f / (1.f + expf(-(acc[i][2] + bgv.z)));
    float bb3 = 1.f / (1.f + expf(-(acc[i][3] + bgv.w)));
    float o0 = o_s[row][tc * 4 + 0], r0 = r_s[row][tc * 4 + 0];
    float o1 = o_s[row][tc * 4 + 1], r1 = r_s[row][tc * 4 + 1];
    float o2 = o_s[row][tc * 4 + 2], r2 = r_s[row][tc * 4 + 2];
    float o3 = o_s[row][tc * 4 + 3], r3 = r_s[row][tc * 4 + 3];
    hm[i][0] = o0 + bb0 * (r0 - o0);
    hm[i][1] = o1 + bb1 * (r1 - o1);
    hm[i][2] = o2 + bb2 * (r2 - o2);
    hm[i][3] = o3 + bb3 * (r3 - o3);
  }
  // per-row mean/var across the 32 lanes of each half-wave (4 cols each)
  float s1[8];
#pragma unroll
  for (int i = 0; i < 8; ++i) s1[i] = hm[i][0] + hm[i][1] + hm[i][2] + hm[i][3];
#pragma unroll
  for (int m = 1; m < 32; m <<= 1)
#pragma unroll
    for (int i = 0; i < 8; ++i) s1[i] += __shfl_xor(s1[i], m);
  float mu[8];
#pragma unroll
  for (int i = 0; i < 8; ++i) mu[i] = s1[i] * (1.f / 128.f);
  float s2[8];
#pragma unroll
  for (int i = 0; i < 8; ++i) {
    float d0 = hm[i][0] - mu[i], d1 = hm[i][1] - mu[i];
    float d2 = hm[i][2] - mu[i], d3 = hm[i][3] - mu[i];
    s2[i] = d0 * d0 + d1 * d1 + d2 * d2 + d3 * d3;
  }
#pragma unroll
  for (int m = 1; m < 32; m <<= 1)
#pragma unroll
    for (int i = 0; i < 8; ++i) s2[i] += __shfl_xor(s2[i], m);
  float4 gv = *(const float4*)(lng + tc * 4);
  float4 bv2 = *(const float4*)(lnb + tc * 4);
#pragma unroll
  for (int i = 0; i < 8; ++i) {
    int row = tr * 8 + i;
    if (row0 + row < M) {
      float rsig = rsqrtf(s2[i] * (1.f / 128.f) + LN_EPS);
      float4 ov;
      ov.x = (hm[i][0] - mu[i]) * rsig * gv.x + bv2.x;
      ov.y = (hm[i][1] - mu[i]) * rsig * gv.y + bv2.y;
      ov.z = (hm[i][2] - mu[i]) * rsig * gv.z + bv2.z;
      ov.w = (hm[i][3] - mu[i]) * rsig * gv.w + bv2.w;
      ov.x = ov.x >= 0.f ? ov.x : NEG * ov.x;
      ov.y = ov.y >= 0.f ? ov.y : NEG * ov.y;
      ov.z = ov.z >= 0.f ? ov.z : NEG * ov.z;
      ov.w = ov.w >= 0.f ? ov.w : NEG * ov.w;
      *(float4*)(xout + (size_t)(row0 + row) * D + tc * 4) = ov;
    }
  }
}

// ---------------- launcher ----------------
extern "C" void kernel_launch(void* const* d_in, const int* in_sizes, int n_in,
                              void* d_out, int out_size, void* d_ws, size_t ws_size,
                              hipStream_t stream) {
  const float* x   = (const float*)d_in[0];
  const float* y   = (const float*)d_in[1];
  const int*   src = (const int*)d_in[2];
  const int*   dst = (const int*)d_in[3];
  const float* Wq = (const float*)d_in[4];  const float* bq = (const float*)d_in[5];
  const float* Wk = (const float*)d_in[6];  const float* bk = (const float*)d_in[7];
  const float* Wv = (const float*)d_in[8];  const float* bv = (const float*)d_in[9];
  const float* We = (const float*)d_in[10]; const float* be = (const float*)d_in[11];
  const float* Wr = (const float*)d_in[12]; const float* br = (const float*)d_in[13];
  const float* Wg = (const float*)d_in[14]; const float* bg = (const float*)d_in[15];
  const float* lng = (const float*)d_in[16]; const float* lnb = (const float*)d_in[17];

  const int N = in_sizes[0] / D;
  const int E = in_sizes[2];

  float* xout   = (float*)d_out;
  float* out_ns = (float*)d_out + (size_t)N * D;

  char* w = (char*)d_ws;
  auto alloc = [&](size_t bytes) -> char* {
    char* p = w;
    w += (bytes + 255) & ~(size_t)255;
    return p;
  };
  float* q  = (float*)alloc((size_t)N * D * 4);
  float* k  = (float*)alloc((size_t)N * D * 4);
  float* v  = (float*)alloc((size_t)N * D * 4);
  float* r  = (float*)alloc((size_t)N * D * 4);
  float* o  = (float*)alloc((size_t)N * D * 4);
  float* escore = (float*)alloc((size_t)E * H * 4);
  int* cnt    = (int*)alloc((size_t)N * 4);
  int* offs   = (int*)alloc((size_t)(N + 1) * 4);
  int* cursor = (int*)alloc((size_t)N * 4);
  int* eids   = (int*)alloc((size_t)E * 4);
  int* bsum   = (int*)alloc(4096);
  size_t used = (size_t)(w - (char*)d_ws);
  bool e32 = (used + (size_t)E * D * 4) <= ws_size;
  void* e = alloc((size_t)E * D * (e32 ? 4 : 2));
  if ((size_t)(w - (char*)d_ws) > ws_size) return;  // cannot run safely

  // CSR build (depends only on dst)
  int nb_scan = (N + 255) / 256;
  k_zero_ints<<<256, 256, 0, stream>>>(cnt, N);
  k_zero_ints<<<256, 256, 0, stream>>>(cursor, N);
  k_count<<<(E + 255) / 256, 256, 0, stream>>>(dst, cnt, E);
  k_scan_part<<<nb_scan, 256, 0, stream>>>(cnt, bsum, N);
  k_scan_mid<<<1, 1, 0, stream>>>(bsum, nb_scan);
  k_scan_fin<<<nb_scan, 256, 0, stream>>>(cnt, bsum, offs, N, E);
  k_scatter<<<(E + 255) / 256, 256, 0, stream>>>(dst, offs, cursor, eids, E);

  // node projections q,k,v,r
  int nbn = (N + 63) / 64;
  PtrQuad pq;
  pq.W[0] = Wq; pq.W[1] = Wk; pq.W[2] = Wv; pq.W[3] = Wr;
  pq.b[0] = bq; pq.b[1] = bk; pq.b[2] = bv; pq.b[3] = br;
  pq.C[0] = q;  pq.C[1] = k;  pq.C[2] = v;  pq.C[3] = r;
  k_nodeproj<<<dim3(nbn, 4), 256, 0, stream>>>(x, pq, N);

  // edge projection + scores
  int nbe = (E + 63) / 64;
  if (e32)
    k_gemm_edge<float><<<nbe, 256, 0, stream>>>(y, We, be, (float*)e, E,
                                                src, dst, q, k, escore);
  else
    k_gemm_edge<unsigned short><<<nbe, 256, 0, stream>>>(y, We, be, (unsigned short*)e, E,
                                                         src, dst, q, k, escore);

  // segment softmax + weighted aggregation
  if (e32)
    k_gather<float><<<N, 128, 0, stream>>>(eids, offs, src, v, (const float*)e,
                                           escore, o, out_ns);
  else
    k_gather<unsigned short><<<N, 128, 0, stream>>>(eids, offs, src, v,
                                                    (const unsigned short*)e,
                                                    escore, o, out_ns);

  // gating + LayerNorm + leaky ReLU
  k_final<<<nbn, 256, 0, stream>>>(o, r, Wg, bg, lng, lnb, xout, N);
}

// Round 2
// 1205.845 us; speedup vs baseline: 1.8714x; 1.8714x over previous
//
#include <hip/hip_runtime.h>

#define DEV __device__ __forceinline__

typedef __bf16 bf16_t;
typedef bf16_t bf16x8 __attribute__((ext_vector_type(8)));
typedef bf16_t bf16x4 __attribute__((ext_vector_type(4)));
typedef float  f32x4  __attribute__((ext_vector_type(4)));

constexpr int D  = 128;
constexpr int H  = 8;
constexpr int HD = 16;
constexpr float EPS_Z   = 1e-8f;
constexpr float LN_EPS  = 1e-5f;
constexpr float NEG     = 0.01f;
constexpr float INV_SQD = 0.25f;   // 1/sqrt(16)

// ---------------- CSR build ----------------
__global__ void k_zero_ints(int* p, long n) {
  long i = (long)blockIdx.x * blockDim.x + threadIdx.x;
  long st = (long)gridDim.x * blockDim.x;
  for (; i < n; i += st) p[i] = 0;
}

__global__ void k_count(const int* __restrict__ dst, int* __restrict__ cnt, int E_) {
  int i = blockIdx.x * blockDim.x + threadIdx.x;
  if (i < E_) atomicAdd(&cnt[dst[i]], 1);
}

__global__ void k_scan_part(const int* __restrict__ cnt, int* __restrict__ bsum, int N_) {
  __shared__ int s[256];
  int i = blockIdx.x * 256 + threadIdx.x;
  s[threadIdx.x] = (i < N_) ? cnt[i] : 0;
  __syncthreads();
  for (int off = 128; off > 0; off >>= 1) {
    if (threadIdx.x < off) s[threadIdx.x] += s[threadIdx.x + off];
    __syncthreads();
  }
  if (threadIdx.x == 0) bsum[blockIdx.x] = s[0];
}

__global__ void k_scan_mid(int* bsum, int nb) {
  if (threadIdx.x == 0 && blockIdx.x == 0) {
    int run = 0;
    for (int i = 0; i < nb; ++i) { int v = bsum[i]; bsum[i] = run; run += v; }
  }
}

__global__ void k_scan_fin(const int* __restrict__ cnt, const int* __restrict__ bsum,
                           int* __restrict__ offs, int N_, int E_) {
  __shared__ int s[256];
  int i = blockIdx.x * 256 + threadIdx.x;
  int v = (i < N_) ? cnt[i] : 0;
  s[threadIdx.x] = v;
  __syncthreads();
  for (int off = 1; off < 256; off <<= 1) {
    int y = (threadIdx.x >= off) ? s[threadIdx.x - off] : 0;
    __syncthreads();
    s[threadIdx.x] += y;
    __syncthreads();
  }
  if (i < N_) offs[i] = bsum[blockIdx.x] + s[threadIdx.x] - v;  // exclusive
  if (blockIdx.x == 0 && threadIdx.x == 0) offs[N_] = E_;
}

__global__ void k_scatter(const int* __restrict__ dst, const int* __restrict__ offs,
                          int* __restrict__ cursor, int* __restrict__ eids, int E_) {
  int i = blockIdx.x * blockDim.x + threadIdx.x;
  if (i < E_) {
    int dn = dst[i];
    int pos = offs[dn] + atomicAdd(&cursor[dn], 1);
    eids[pos] = i;
  }
}

// ---------------- W fragment packing ----------------
// pk[(kc*8+ct)*64 + lane][j] = W[kc*32 + (lane>>4)*8 + j][ct*16 + (lane&15)]
// hi = rtn bf16, lo = rtn bf16 of residual. Same (lane,j)->k map as A frags.
struct PackArgs {
  const float* W[6];
  bf16_t* hi[6];
  bf16_t* lo[6];
  int K[6];
};

__global__ __launch_bounds__(256)
void k_packw(PackArgs pa) {
  int wid = blockIdx.y;
  int K = pa.K[wid];
  int tid = blockIdx.x * 256 + threadIdx.x;
  if (tid >= K * 16) return;
  int lane = tid & 63;
  int tt = tid >> 6;          // kc*8 + ct
  int ct = tt & 7, kc = tt >> 3;
  int col = ct * 16 + (lane & 15);
  int kbase = kc * 32 + (lane >> 4) * 8;
  const float* W = pa.W[wid];
  bf16_t* ph = pa.hi[wid] + (size_t)tid * 8;
  bf16_t* pl = pa.lo[wid] + (size_t)tid * 8;
#pragma unroll
  for (int j = 0; j < 8; ++j) {
    float f = W[(size_t)(kbase + j) * D + col];
    bf16_t h = (bf16_t)f;
    bf16_t l = (bf16_t)(f - (float)h);
    ph[j] = h;
    pl[j] = l;
  }
}

// ---------------- LDS swizzle for A tiles (64x128 bf16, row stride 256B) ----------------
DEV int swzA(int row, int kbyte) { return (row * 256 + kbyte) ^ ((row & 7) << 4); }

DEV void stage_split_row(float f0, float f1, float f2, float f3,
                         char* hb, char* lb, int off) {
  bf16x4 h, l;
  h[0] = (bf16_t)f0; l[0] = (bf16_t)(f0 - (float)h[0]);
  h[1] = (bf16_t)f1; l[1] = (bf16_t)(f1 - (float)h[1]);
  h[2] = (bf16_t)f2; l[2] = (bf16_t)(f2 - (float)h[2]);
  h[3] = (bf16_t)f3; l[3] = (bf16_t)(f3 - (float)h[3]);
  *(bf16x4*)(hb + off) = h;
  *(bf16x4*)(lb + off) = l;
}

// ---------------- MFMA GEMM body: C[M,128] = A[M,128]@W + b ----------------
// 256 thr = 4 waves; block tile 64 rows x 128 cols; wave w owns rows w*16..+15.
// Split bf16: acc += ah*wh + al*wh + ah*wl  (fp32 acc => ~fp32 accuracy).
template<int EPI>
DEV void mfma_gemm_body(const float* __restrict__ A,
                        const bf16_t* __restrict__ pkh, const bf16_t* __restrict__ pkl,
                        const float* __restrict__ bias,
                        float* __restrict__ Cf, bf16_t* __restrict__ Cb, int M,
                        const int* __restrict__ src, const int* __restrict__ dst,
                        const float* __restrict__ qm, const float* __restrict__ km,
                        float* __restrict__ escore, char* smem) {
  char* ahi = smem;
  char* alo = smem + 16384;
  float* e_s = (float*)smem;      // [64][132] fp32, aliases ahi/alo after compute
  const int t = threadIdx.x;
  const int row0 = blockIdx.x * 64;

  // stage A as bf16 hi/lo, swizzled
#pragma unroll
  for (int i = 0; i < 8; ++i) {
    int f = t + i * 256;
    int row = f >> 5, c4 = f & 31;
    float4 v4 = make_float4(0.f, 0.f, 0.f, 0.f);
    if (row0 + row < M) v4 = *(const float4*)(A + (size_t)(row0 + row) * D + c4 * 4);
    stage_split_row(v4.x, v4.y, v4.z, v4.w, ahi, alo, swzA(row, c4 * 8));
  }
  __syncthreads();

  const int lane = t & 63, w = t >> 6;
  const int fr = lane & 15, fg = lane >> 4;
  f32x4 acc[8];
#pragma unroll
  for (int ct = 0; ct < 8; ++ct) acc[ct] = (f32x4){0.f, 0.f, 0.f, 0.f};

  const bf16x8* Ph = (const bf16x8*)pkh + lane;
  const bf16x8* Pl = (const bf16x8*)pkl + lane;
#pragma unroll
  for (int kc = 0; kc < 4; ++kc) {
    int aoff = swzA(w * 16 + fr, kc * 64 + fg * 16);
    bf16x8 ah = *(const bf16x8*)(ahi + aoff);
    bf16x8 al = *(const bf16x8*)(alo + aoff);
    const bf16x8* ph = Ph + kc * 512;
    const bf16x8* pl = Pl + kc * 512;
#pragma unroll
    for (int ct = 0; ct < 8; ++ct) {
      bf16x8 wh = ph[ct * 64];
      bf16x8 wl = pl[ct * 64];
      acc[ct] = __builtin_amdgcn_mfma_f32_16x16x32_bf16(ah, wh, acc[ct], 0, 0, 0);
      acc[ct] = __builtin_amdgcn_mfma_f32_16x16x32_bf16(al, wh, acc[ct], 0, 0, 0);
      acc[ct] = __builtin_amdgcn_mfma_f32_16x16x32_bf16(ah, wl, acc[ct], 0, 0, 0);
    }
  }
  __syncthreads();   // A tile dead; reuse as e_s

  // acc + bias -> e_s (fp32, pad 132)
#pragma unroll
  for (int ct = 0; ct < 8; ++ct) {
    int col = ct * 16 + fr;
    float b = bias[col];
#pragma unroll
    for (int p = 0; p < 4; ++p) {
      int row = w * 16 + fg * 4 + p;
      e_s[row * 132 + col] = acc[ct][p] + b;
    }
  }
  __syncthreads();

  if (EPI == 0) {
#pragma unroll
    for (int i = 0; i < 8; ++i) {
      int f = t + i * 256;
      int row = f >> 5, c4 = f & 31;
      if (row0 + row < M)
        *(float4*)(Cf + (size_t)(row0 + row) * D + c4 * 4) =
            *(const float4*)&e_s[row * 132 + c4 * 4];
    }
  } else {
    // e -> global as bf16 (coalesced)
#pragma unroll
    for (int i = 0; i < 8; ++i) {
      int f = t + i * 256;
      int row = f >> 5, c4 = f & 31;
      if (row0 + row < M) {
        float4 ev = *(const float4*)&e_s[row * 132 + c4 * 4];
        bf16x4 h;
        h[0] = (bf16_t)ev.x; h[1] = (bf16_t)ev.y;
        h[2] = (bf16_t)ev.z; h[3] = (bf16_t)ev.w;
        *(bf16x4*)(Cb + (size_t)(row0 + row) * D + c4 * 4) = h;
      }
    }
    // scores: 512 (row,h) pairs, 2 per thread
#pragma unroll
    for (int pp = 0; pp < 2; ++pp) {
      int p = t + pp * 256;
      int row = p >> 3, h = p & 7;
      int grow = row0 + row;
      if (grow < M) {
        int s_ = src[grow], d_ = dst[grow];
        const float* qp = qm + (size_t)d_ * D + h * HD;
        const float* kp = km + (size_t)s_ * D + h * HD;
        float sc = 0.f;
#pragma unroll
        for (int i2 = 0; i2 < 4; ++i2) {
          float4 qv = *(const float4*)(qp + i2 * 4);
          float4 kv = *(const float4*)(kp + i2 * 4);
          float4 ev = *(const float4*)&e_s[row * 132 + h * HD + i2 * 4];
          sc += qv.x * (kv.x + ev.x) + qv.y * (kv.y + ev.y) +
                qv.z * (kv.z + ev.z) + qv.w * (kv.w + ev.w);
        }
        escore[(size_t)grow * H + h] = expf(sc);
      }
    }
  }
}

struct NP {
  const bf16_t* pkh[4];
  const bf16_t* pkl[4];
  const float*  b[4];
  float*        C[4];
};

__global__ __launch_bounds__(256)
void k_nodeproj(const float* __restrict__ x, NP np, int M) {
  __shared__ __align__(16) char smem[64 * 132 * 4];
  int wi = blockIdx.y;
  mfma_gemm_body<0>(x, np.pkh[wi], np.pkl[wi], np.b[wi], np.C[wi], nullptr, M,
                    nullptr, nullptr, nullptr, nullptr, nullptr, smem);
}

__global__ __launch_bounds__(256)
void k_gemm_edge(const float* __restrict__ y,
                 const bf16_t* __restrict__ pkh, const bf16_t* __restrict__ pkl,
                 const float* __restrict__ be, bf16_t* __restrict__ e, int M,
                 const int* __restrict__ src, const int* __restrict__ dst,
                 const float* __restrict__ q, const float* __restrict__ k,
                 float* __restrict__ esc) {
  __shared__ __align__(16) char smem[64 * 132 * 4];
  mfma_gemm_body<1>(y, pkh, pkl, be, nullptr, e, M, src, dst, q, k, esc, smem);
}

// ---------------- gather: z, o, norm_escore per destination node ----------------
__global__ __launch_bounds__(128)
void k_gather(const int* __restrict__ eids_all, const int* __restrict__ offs,
              const int* __restrict__ src, const float* __restrict__ vmat,
              const bf16_t* __restrict__ emat, const float* __restrict__ escore,
              float* __restrict__ o, float* __restrict__ out_ns) {
  int nid = blockIdx.x;
  int t = threadIdx.x;          // 0..127 ; h = t>>4
  int h = t >> 4;
  int beg = offs[nid], end = offs[nid + 1];
  __shared__ int eids[128];
  __shared__ int srcs[128];
  float z0 = 0.f, z1 = 0.f;
  for (int c0 = beg; c0 < end; c0 += 128) {
    int cnt = min(128, end - c0);
    __syncthreads();
    if (t < cnt) eids[t] = eids_all[c0 + t];
    __syncthreads();
    int j = 0;
    for (; j + 1 < cnt; j += 2) {
      z0 += escore[(size_t)eids[j] * H + h];
      z1 += escore[(size_t)eids[j + 1] * H + h];
    }
    if (j < cnt) z0 += escore[(size_t)eids[j] * H + h];
  }
  float inv = INV_SQD / (EPS_Z + (z0 + z1));
  float acc0 = 0.f, acc1 = 0.f;
  for (int c0 = beg; c0 < end; c0 += 128) {
    int cnt = min(128, end - c0);
    __syncthreads();
    if (t < cnt) { int e_ = eids_all[c0 + t]; eids[t] = e_; srcs[t] = src[e_]; }
    __syncthreads();
    int j = 0;
    for (; j + 1 < cnt; j += 2) {
      int e0 = eids[j], e1 = eids[j + 1];
      float es0 = escore[(size_t)e0 * H + h];
      float es1 = escore[(size_t)e1 * H + h];
      float ev0 = (float)emat[(size_t)e0 * D + t];
      float ev1 = (float)emat[(size_t)e1 * D + t];
      float vv0 = vmat[(size_t)srcs[j] * D + t];
      float vv1 = vmat[(size_t)srcs[j + 1] * D + t];
      float ns0 = es0 * inv, ns1 = es1 * inv;
      if ((t & 15) == 0) {
        out_ns[(size_t)e0 * H + h] = ns0;
        out_ns[(size_t)e1 * H + h] = ns1;
      }
      acc0 += ns0 * (vv0 + ev0);
      acc1 += ns1 * (vv1 + ev1);
    }
    if (j < cnt) {
      int e0 = eids[j];
      float es0 = escore[(size_t)e0 * H + h];
      float ev0 = (float)emat[(size_t)e0 * D + t];
      float vv0 = vmat[(size_t)srcs[j] * D + t];
      float ns0 = es0 * inv;
      if ((t & 15) == 0) out_ns[(size_t)e0 * H + h] = ns0;
      acc0 += ns0 * (vv0 + ev0);
    }
  }
  o[(size_t)nid * D + t] = acc0 + acc1;
}

// ---------------- final: gating GEMM (bf16 1-pass) + mix + LN + leaky ----------------
__global__ __launch_bounds__(256)
void k_final(const float* __restrict__ o, const float* __restrict__ r,
             const bf16_t* __restrict__ pkg,   // packed Wg frags, K=384
             const float* __restrict__ bg,
             const float* __restrict__ lng, const float* __restrict__ lnb,
             float* __restrict__ xout, int M) {
  __shared__ __align__(16) char smem[3 * 64 * 128 * 2];   // 48 KB: 3 bf16 segments
  float* e_s = (float*)smem;                               // [64][132] fp32 alias
  const int t = threadIdx.x;
  const int row0 = blockIdx.x * 64;

  // stage cat = [o | r | o-r] as bf16 (single precision: gate path only)
#pragma unroll
  for (int i = 0; i < 8; ++i) {
    int f = t + i * 256;
    int row = f >> 5, c4 = f & 31;
    float4 ov = make_float4(0.f, 0.f, 0.f, 0.f), rv = ov;
    if (row0 + row < M) {
      ov = *(const float4*)(o + (size_t)(row0 + row) * D + c4 * 4);
      rv = *(const float4*)(r + (size_t)(row0 + row) * D + c4 * 4);
    }
    int off = swzA(row, c4 * 8);
    bf16x4 hv;
    hv[0] = (bf16_t)ov.x; hv[1] = (bf16_t)ov.y; hv[2] = (bf16_t)ov.z; hv[3] = (bf16_t)ov.w;
    *(bf16x4*)(smem + off) = hv;
    hv[0] = (bf16_t)rv.x; hv[1] = (bf16_t)rv.y; hv[2] = (bf16_t)rv.z; hv[3] = (bf16_t)rv.w;
    *(bf16x4*)(smem + 16384 + off) = hv;
    hv[0] = (bf16_t)(ov.x - rv.x); hv[1] = (bf16_t)(ov.y - rv.y);
    hv[2] = (bf16_t)(ov.z - rv.z); hv[3] = (bf16_t)(ov.w - rv.w);
    *(bf16x4*)(smem + 32768 + off) = hv;
  }
  __syncthreads();

  const int lane = t & 63, w = t >> 6;
  const int fr = lane & 15, fg = lane >> 4;
  f32x4 acc[8];
#pragma unroll
  for (int ct = 0; ct < 8; ++ct) acc[ct] = (f32x4){0.f, 0.f, 0.f, 0.f};

#pragma unroll
  for (int s = 0; s < 3; ++s) {
    char* base = smem + s * 16384;
    const bf16x8* Ph = (const bf16x8*)pkg + lane + s * 2048;  // kc_global = s*4+kc
#pragma unroll
    for (int kc = 0; kc < 4; ++kc) {
      bf16x8 ah = *(const bf16x8*)(base + swzA(w * 16 + fr, kc * 64 + fg * 16));
      const bf16x8* ph = Ph + kc * 512;
#pragma unroll
      for (int ct = 0; ct < 8; ++ct)
        acc[ct] = __builtin_amdgcn_mfma_f32_16x16x32_bf16(ah, ph[ct * 64], acc[ct], 0, 0, 0);
    }
  }
  __syncthreads();

#pragma unroll
  for (int ct = 0; ct < 8; ++ct) {
    int col = ct * 16 + fr;
    float b = bg[col];
#pragma unroll
    for (int p = 0; p < 4; ++p) {
      int row = w * 16 + fg * 4 + p;
      e_s[row * 132 + col] = acc[ct][p] + b;
    }
  }
  __syncthreads();

  // epilogue: sigmoid gate, mix with fp32 o/r from global, LN per row, leaky
#pragma unroll
  for (int i = 0; i < 8; ++i) {
    int f = t + i * 256;
    int row = f >> 5, c4 = f & 31;
    int grow = row0 + row;
    float4 g4 = *(const float4*)&e_s[row * 132 + c4 * 4];
    float4 ov = make_float4(0.f, 0.f, 0.f, 0.f), rv = ov;
    if (grow < M) {
      ov = *(const float4*)(o + (size_t)grow * D + c4 * 4);
      rv = *(const float4*)(r + (size_t)grow * D + c4 * 4);
    }
    float b0 = 1.f / (1.f + expf(-g4.x));
    float b1 = 1.f / (1.f + expf(-g4.y));
    float b2 = 1.f / (1.f + expf(-g4.z));
    float b3 = 1.f / (1.f + expf(-g4.w));
    float h0 = ov.x + b0 * (rv.x - ov.x);
    float h1 = ov.y + b1 * (rv.y - ov.y);
    float h2 = ov.z + b2 * (rv.z - ov.z);
    float h3 = ov.w + b3 * (rv.w - ov.w);
    // LN: lanes (t&31)=0..31 of each half-wave hold the same row
    float s1 = h0 + h1 + h2 + h3;
#pragma unroll
    for (int m = 1; m < 32; m <<= 1) s1 += __shfl_xor(s1, m);
    float mu = s1 * (1.f / 128.f);
    float d0 = h0 - mu, d1 = h1 - mu, d2 = h2 - mu, d3 = h3 - mu;
    float s2 = d0 * d0 + d1 * d1 + d2 * d2 + d3 * d3;
#pragma unroll
    for (int m = 1; m < 32; m <<= 1) s2 += __shfl_xor(s2, m);
    float rsig = rsqrtf(s2 * (1.f / 128.f) + LN_EPS);
    float4 gv  = *(const float4*)(lng + c4 * 4);
    float4 bv2 = *(const float4*)(lnb + c4 * 4);
    float4 res;
    res.x = d0 * rsig * gv.x + bv2.x;
    res.y = d1 * rsig * gv.y + bv2.y;
    res.z = d2 * rsig * gv.z + bv2.z;
    res.w = d3 * rsig * gv.w + bv2.w;
    res.x = res.x >= 0.f ? res.x : NEG * res.x;
    res.y = res.y >= 0.f ? res.y : NEG * res.y;
    res.z = res.z >= 0.f ? res.z : NEG * res.z;
    res.w = res.w >= 0.f ? res.w : NEG * res.w;
    if (grow < M)
      *(float4*)(xout + (size_t)grow * D + c4 * 4) = res;
  }
}

// ---------------- launcher ----------------
extern "C" void kernel_launch(void* const* d_in, const int* in_sizes, int n_in,
                              void* d_out, int out_size, void* d_ws, size_t ws_size,
                              hipStream_t stream) {
  const float* x   = (const float*)d_in[0];
  const float* y   = (const float*)d_in[1];
  const int*   src = (const int*)d_in[2];
  const int*   dst = (const int*)d_in[3];
  const float* Wq = (const float*)d_in[4];  const float* bq = (const float*)d_in[5];
  const float* Wk = (const float*)d_in[6];  const float* bk = (const float*)d_in[7];
  const float* Wv = (const float*)d_in[8];  const float* bv = (const float*)d_in[9];
  const float* We = (const float*)d_in[10]; const float* be = (const float*)d_in[11];
  const float* Wr = (const float*)d_in[12]; const float* br = (const float*)d_in[13];
  const float* Wg = (const float*)d_in[14]; const float* bg = (const float*)d_in[15];
  const float* lng = (const float*)d_in[16]; const float* lnb = (const float*)d_in[17];

  const int N = in_sizes[0] / D;
  const int E = in_sizes[2];

  float* xout   = (float*)d_out;
  float* out_ns = (float*)d_out + (size_t)N * D;

  char* w = (char*)d_ws;
  auto alloc = [&](size_t bytes) -> char* {
    char* p = w;
    w += (bytes + 255) & ~(size_t)255;
    return p;
  };
  float* q  = (float*)alloc((size_t)N * D * 4);
  float* k  = (float*)alloc((size_t)N * D * 4);
  float* v  = (float*)alloc((size_t)N * D * 4);
  float* r  = (float*)alloc((size_t)N * D * 4);
  float* o  = (float*)alloc((size_t)N * D * 4);
  float* escore = (float*)alloc((size_t)E * H * 4);
  int* cnt    = (int*)alloc((size_t)N * 4);
  int* offs   = (int*)alloc((size_t)(N + 1) * 4);
  int* cursor = (int*)alloc((size_t)N * 4);
  int* eids   = (int*)alloc((size_t)E * 4);
  int* bsum   = (int*)alloc(4096);
  // packed W fragments
  bf16_t* pk_hi[6];
  bf16_t* pk_lo[6];
  const float* Ws[6] = {Wq, Wk, Wv, Wr, We, Wg};
  int Ks[6] = {D, D, D, D, D, 3 * D};
  for (int i = 0; i < 6; ++i) {
    pk_hi[i] = (bf16_t*)alloc((size_t)Ks[i] * D * 2);
    pk_lo[i] = (bf16_t*)alloc((size_t)Ks[i] * D * 2);
  }
  bf16_t* e = (bf16_t*)alloc((size_t)E * D * 2);
  if ((size_t)(w - (char*)d_ws) > ws_size) return;  // cannot run safely

  // pack W fragments (independent of everything else)
  PackArgs pa;
  for (int i = 0; i < 6; ++i) {
    pa.W[i] = Ws[i]; pa.hi[i] = pk_hi[i]; pa.lo[i] = pk_lo[i]; pa.K[i] = Ks[i];
  }
  k_packw<<<dim3(24, 6), 256, 0, stream>>>(pa);

  // CSR build (depends only on dst)
  int nb_scan = (N + 255) / 256;
  k_zero_ints<<<256, 256, 0, stream>>>(cnt, N);
  k_zero_ints<<<256, 256, 0, stream>>>(cursor, N);
  k_count<<<(E + 255) / 256, 256, 0, stream>>>(dst, cnt, E);
  k_scan_part<<<nb_scan, 256, 0, stream>>>(cnt, bsum, N);
  k_scan_mid<<<1, 1, 0, stream>>>(bsum, nb_scan);
  k_scan_fin<<<nb_scan, 256, 0, stream>>>(cnt, bsum, offs, N, E);
  k_scatter<<<(E + 255) / 256, 256, 0, stream>>>(dst, offs, cursor, eids, E);

  // node projections q,k,v,r (split bf16 MFMA)
  int nbn = (N + 63) / 64;
  NP np;
  np.pkh[0] = pk_hi[0]; np.pkl[0] = pk_lo[0]; np.b[0] = bq; np.C[0] = q;
  np.pkh[1] = pk_hi[1]; np.pkl[1] = pk_lo[1]; np.b[1] = bk; np.C[1] = k;
  np.pkh[2] = pk_hi[2]; np.pkl[2] = pk_lo[2]; np.b[2] = bv; np.C[2] = v;
  np.pkh[3] = pk_hi[3]; np.pkl[3] = pk_lo[3]; np.b[3] = br; np.C[3] = r;
  k_nodeproj<<<dim3(nbn, 4), 256, 0, stream>>>(x, np, N);

  // edge projection + scores (split bf16 MFMA + fused score epilogue)
  int nbe = (E + 63) / 64;
  k_gemm_edge<<<nbe, 256, 0, stream>>>(y, pk_hi[4], pk_lo[4], be, e, E,
                                       src, dst, q, k, escore);

  // segment softmax + weighted aggregation
  k_gather<<<N, 128, 0, stream>>>(eids, offs, src, v, e, escore, o, out_ns);

  // gating + LayerNorm + leaky ReLU
  k_final<<<nbn, 256, 0, stream>>>(o, r, pk_hi[5], bg, lng, lnb, xout, N);
}

// Round 3
// 1091.686 us; speedup vs baseline: 2.0671x; 1.1046x over previous
//
#include <hip/hip_runtime.h>

#define DEV __device__ __forceinline__

typedef __bf16 bf16_t;
typedef bf16_t bf16x8 __attribute__((ext_vector_type(8)));
typedef bf16_t bf16x4 __attribute__((ext_vector_type(4)));
typedef float  f32x4  __attribute__((ext_vector_type(4)));

constexpr int D  = 128;
constexpr int H  = 8;
constexpr float EPS_Z   = 1e-8f;
constexpr float LN_EPS  = 1e-5f;
constexpr float NEG     = 0.01f;
constexpr float INV_SQD = 0.25f;   // 1/sqrt(16)

// ---------------- CSR build ----------------
__global__ void k_zero_ints(int* p, long n) {
  long i = (long)blockIdx.x * blockDim.x + threadIdx.x;
  long st = (long)gridDim.x * blockDim.x;
  for (; i < n; i += st) p[i] = 0;
}

__global__ void k_count(const int* __restrict__ dst, int* __restrict__ cnt, int E_) {
  int i = blockIdx.x * blockDim.x + threadIdx.x;
  if (i < E_) atomicAdd(&cnt[dst[i]], 1);
}

__global__ void k_scan_part(const int* __restrict__ cnt, int* __restrict__ bsum, int N_) {
  __shared__ int s[256];
  int i = blockIdx.x * 256 + threadIdx.x;
  s[threadIdx.x] = (i < N_) ? cnt[i] : 0;
  __syncthreads();
  for (int off = 128; off > 0; off >>= 1) {
    if (threadIdx.x < off) s[threadIdx.x] += s[threadIdx.x + off];
    __syncthreads();
  }
  if (threadIdx.x == 0) bsum[blockIdx.x] = s[0];
}

__global__ void k_scan_mid(int* bsum, int nb) {
  if (threadIdx.x == 0 && blockIdx.x == 0) {
    int run = 0;
    for (int i = 0; i < nb; ++i) { int v = bsum[i]; bsum[i] = run; run += v; }
  }
}

__global__ void k_scan_fin(const int* __restrict__ cnt, const int* __restrict__ bsum,
                           int* __restrict__ offs, int N_, int E_) {
  __shared__ int s[256];
  int i = blockIdx.x * 256 + threadIdx.x;
  int v = (i < N_) ? cnt[i] : 0;
  s[threadIdx.x] = v;
  __syncthreads();
  for (int off = 1; off < 256; off <<= 1) {
    int y = (threadIdx.x >= off) ? s[threadIdx.x - off] : 0;
    __syncthreads();
    s[threadIdx.x] += y;
    __syncthreads();
  }
  if (i < N_) offs[i] = bsum[blockIdx.x] + s[threadIdx.x] - v;  // exclusive
  if (blockIdx.x == 0 && threadIdx.x == 0) offs[N_] = E_;
}

__global__ void k_scatter(const int* __restrict__ dst, const int* __restrict__ offs,
                          int* __restrict__ cursor, int* __restrict__ eids, int E_) {
  int i = blockIdx.x * blockDim.x + threadIdx.x;
  if (i < E_) {
    int dn = dst[i];
    int pos = offs[dn] + atomicAdd(&cursor[dn], 1);
    eids[pos] = i;
  }
}

// ---------------- W fragment packing ----------------
// pk[(kc*8+ct)*64 + lane][j] = W[kc*32 + (lane>>4)*8 + j][ct*16 + (lane&15)]
struct PackArgs {
  const float* W[6];
  bf16_t* hi[6];
  bf16_t* lo[6];
  int K[6];
};

__global__ __launch_bounds__(256)
void k_packw(PackArgs pa) {
  int wid = blockIdx.y;
  int K = pa.K[wid];
  int tid = blockIdx.x * 256 + threadIdx.x;
  if (tid >= K * 16) return;
  int lane = tid & 63;
  int tt = tid >> 6;          // kc*8 + ct
  int ct = tt & 7, kc = tt >> 3;
  int col = ct * 16 + (lane & 15);
  int kbase = kc * 32 + (lane >> 4) * 8;
  const float* W = pa.W[wid];
  bf16_t* ph = pa.hi[wid] + (size_t)tid * 8;
  bf16_t* pl = pa.lo[wid] + (size_t)tid * 8;
#pragma unroll
  for (int j = 0; j < 8; ++j) {
    float f = W[(size_t)(kbase + j) * D + col];
    bf16_t h = (bf16_t)f;
    bf16_t l = (bf16_t)(f - (float)h);
    ph[j] = h;
    pl[j] = l;
  }
}

// ---------------- LDS swizzle for A tiles (64x128 bf16, row stride 256B) ----------------
DEV int swzA(int row, int kbyte) { return (row * 256 + kbyte) ^ ((row & 7) << 4); }

DEV void stage_split_row(float f0, float f1, float f2, float f3,
                         char* hb, char* lb, int off) {
  bf16x4 h, l;
  h[0] = (bf16_t)f0; l[0] = (bf16_t)(f0 - (float)h[0]);
  h[1] = (bf16_t)f1; l[1] = (bf16_t)(f1 - (float)h[1]);
  h[2] = (bf16_t)f2; l[2] = (bf16_t)(f2 - (float)h[2]);
  h[3] = (bf16_t)f3; l[3] = (bf16_t)(f3 - (float)h[3]);
  *(bf16x4*)(hb + off) = h;
  *(bf16x4*)(lb + off) = l;
}

// ---------------- node projections: C[M,128] = A[M,128]@W + b (fp32 out) ----------------
struct NP {
  const bf16_t* pkh[4];
  const bf16_t* pkl[4];
  const float*  b[4];
  float*        C[4];
};

__global__ __launch_bounds__(256)
void k_nodeproj(const float* __restrict__ A, NP np, int M) {
  __shared__ __align__(16) char smem[64 * 132 * 4];
  char* ahi = smem;
  char* alo = smem + 16384;
  float* e_s = (float*)smem;      // [64][132] fp32 alias
  const int wi = blockIdx.y;
  const bf16_t* pkh = np.pkh[wi];
  const bf16_t* pkl = np.pkl[wi];
  const float* bias = np.b[wi];
  float* Cf = np.C[wi];
  const int t = threadIdx.x;
  const int row0 = blockIdx.x * 64;

#pragma unroll
  for (int i = 0; i < 8; ++i) {
    int f = t + i * 256;
    int row = f >> 5, c4 = f & 31;
    float4 v4 = make_float4(0.f, 0.f, 0.f, 0.f);
    if (row0 + row < M) v4 = *(const float4*)(A + (size_t)(row0 + row) * D + c4 * 4);
    stage_split_row(v4.x, v4.y, v4.z, v4.w, ahi, alo, swzA(row, c4 * 8));
  }
  __syncthreads();

  const int lane = t & 63, w = t >> 6;
  const int fr = lane & 15, fg = lane >> 4;
  f32x4 acc[8];
#pragma unroll
  for (int ct = 0; ct < 8; ++ct) acc[ct] = (f32x4){0.f, 0.f, 0.f, 0.f};

  const bf16x8* Ph = (const bf16x8*)pkh + lane;
  const bf16x8* Pl = (const bf16x8*)pkl + lane;
#pragma unroll
  for (int kc = 0; kc < 4; ++kc) {
    int aoff = swzA(w * 16 + fr, kc * 64 + fg * 16);
    bf16x8 ah = *(const bf16x8*)(ahi + aoff);
    bf16x8 al = *(const bf16x8*)(alo + aoff);
    const bf16x8* ph = Ph + kc * 512;
    const bf16x8* pl = Pl + kc * 512;
#pragma unroll
    for (int ct = 0; ct < 8; ++ct) {
      bf16x8 wh = ph[ct * 64];
      bf16x8 wl = pl[ct * 64];
      acc[ct] = __builtin_amdgcn_mfma_f32_16x16x32_bf16(ah, wh, acc[ct], 0, 0, 0);
      acc[ct] = __builtin_amdgcn_mfma_f32_16x16x32_bf16(al, wh, acc[ct], 0, 0, 0);
      acc[ct] = __builtin_amdgcn_mfma_f32_16x16x32_bf16(ah, wl, acc[ct], 0, 0, 0);
    }
  }
  __syncthreads();

#pragma unroll
  for (int ct = 0; ct < 8; ++ct) {
    int col = ct * 16 + fr;
    float b = bias[col];
#pragma unroll
    for (int p = 0; p < 4; ++p) {
      int row = w * 16 + fg * 4 + p;
      e_s[row * 132 + col] = acc[ct][p] + b;
    }
  }
  __syncthreads();
#pragma unroll
  for (int i = 0; i < 8; ++i) {
    int f = t + i * 256;
    int row = f >> 5, c4 = f & 31;
    if (row0 + row < M)
      *(float4*)(Cf + (size_t)(row0 + row) * D + c4 * 4) =
          *(const float4*)&e_s[row * 132 + c4 * 4];
  }
}

// ---------------- edge GEMM: e[E,128] = y@We + be (bf16 out), pipelined ----------------
__global__ __launch_bounds__(256)
void k_gemm_edge(const float* __restrict__ A,
                 const bf16_t* __restrict__ pkh, const bf16_t* __restrict__ pkl,
                 const float* __restrict__ bias, bf16_t* __restrict__ C,
                 int M, int ntiles) {
  __shared__ __align__(16) char smem[32768];
  char* ahi = smem;
  char* alo = smem + 16384;
  bf16_t* e_s = (bf16_t*)smem;            // [64][136] alias (17408 B)
  const int t = threadIdx.x;
  const int lane = t & 63, w = t >> 6;
  const int fr = lane & 15, fg = lane >> 4;

  float bfrag[8];
#pragma unroll
  for (int ct = 0; ct < 8; ++ct) bfrag[ct] = bias[ct * 16 + fr];

  const bf16x8* Ph = (const bf16x8*)pkh + lane;
  const bf16x8* Pl = (const bf16x8*)pkl + lane;

  float4 sreg[8];
  int tile = blockIdx.x;
  if (tile < ntiles) {
    int row0 = tile * 64;
#pragma unroll
    for (int i = 0; i < 8; ++i) {
      int f = t + i * 256, row = f >> 5, c4 = f & 31;
      sreg[i] = (row0 + row < M) ? *(const float4*)(A + (size_t)(row0 + row) * D + c4 * 4)
                                 : make_float4(0.f, 0.f, 0.f, 0.f);
    }
  }
  while (tile < ntiles) {
    int row0 = tile * 64;
    __syncthreads();            // previous iteration's e_s readers are done
#pragma unroll
    for (int i = 0; i < 8; ++i) {
      int f = t + i * 256, row = f >> 5, c4 = f & 31;
      stage_split_row(sreg[i].x, sreg[i].y, sreg[i].z, sreg[i].w, ahi, alo,
                      swzA(row, c4 * 8));
    }
    __syncthreads();
    bf16x8 ah[4], al[4];
#pragma unroll
    for (int kc = 0; kc < 4; ++kc) {
      int aoff = swzA(w * 16 + fr, kc * 64 + fg * 16);
      ah[kc] = *(const bf16x8*)(ahi + aoff);
      al[kc] = *(const bf16x8*)(alo + aoff);
    }
    // prefetch next tile's A while MFMAs run
    int ntile = tile + gridDim.x;
    if (ntile < ntiles) {
      int nrow0 = ntile * 64;
#pragma unroll
      for (int i = 0; i < 8; ++i) {
        int f = t + i * 256, row = f >> 5, c4 = f & 31;
        sreg[i] = (nrow0 + row < M)
                      ? *(const float4*)(A + (size_t)(nrow0 + row) * D + c4 * 4)
                      : make_float4(0.f, 0.f, 0.f, 0.f);
      }
    }
    f32x4 acc[8];
#pragma unroll
    for (int ct = 0; ct < 8; ++ct) acc[ct] = (f32x4){0.f, 0.f, 0.f, 0.f};
#pragma unroll
    for (int kc = 0; kc < 4; ++kc) {
      const bf16x8* ph = Ph + kc * 512;
      const bf16x8* pl = Pl + kc * 512;
#pragma unroll
      for (int ct = 0; ct < 8; ++ct) {
        bf16x8 wh = ph[ct * 64];
        bf16x8 wl = pl[ct * 64];
        acc[ct] = __builtin_amdgcn_mfma_f32_16x16x32_bf16(ah[kc], wh, acc[ct], 0, 0, 0);
        acc[ct] = __builtin_amdgcn_mfma_f32_16x16x32_bf16(al[kc], wh, acc[ct], 0, 0, 0);
        acc[ct] = __builtin_amdgcn_mfma_f32_16x16x32_bf16(ah[kc], wl, acc[ct], 0, 0, 0);
      }
    }
    __syncthreads();            // all waves' ds_reads of ahi/alo complete
#pragma unroll
    for (int ct = 0; ct < 8; ++ct) {
      int col = ct * 16 + fr;
#pragma unroll
      for (int p = 0; p < 4; ++p) {
        int row = w * 16 + fg * 4 + p;
        e_s[row * 136 + col] = (bf16_t)(acc[ct][p] + bfrag[ct]);
      }
    }
    __syncthreads();
#pragma unroll
    for (int i = 0; i < 4; ++i) {
      int row = i * 16 + (t >> 4), c8 = t & 15;
      if (row0 + row < M)
        *(bf16x8*)(C + (size_t)(row0 + row) * D + c8 * 8) =
            *(const bf16x8*)&e_s[row * 136 + c8 * 8];
    }
    tile = ntile;
  }
}

// ---------------- score: escore[e,h] = exp(q[dst].(k[src]+e)) ----------------
__global__ __launch_bounds__(256)
void k_score(const int* __restrict__ src, const int* __restrict__ dst,
             const float* __restrict__ q, const float* __restrict__ k,
             const bf16_t* __restrict__ e, float* __restrict__ escore, int E_) {
  int tid = blockIdx.x * 256 + threadIdx.x;
  if (tid >= E_ * H) return;
  int eg = tid >> 3, h = tid & 7;
  int s_ = src[eg], d_ = dst[eg];
  const float* qp = q + (size_t)d_ * D + h * 16;
  const float* kp = k + (size_t)s_ * D + h * 16;
  const bf16_t* ep = e + (size_t)eg * D + h * 16;
  bf16x8 e0 = *(const bf16x8*)ep;
  bf16x8 e1 = *(const bf16x8*)(ep + 8);
  float sc = 0.f;
#pragma unroll
  for (int i = 0; i < 2; ++i) {
    float4 qv = *(const float4*)(qp + i * 4);
    float4 kv = *(const float4*)(kp + i * 4);
    sc += qv.x * (kv.x + (float)e0[i * 4 + 0]) + qv.y * (kv.y + (float)e0[i * 4 + 1]) +
          qv.z * (kv.z + (float)e0[i * 4 + 2]) + qv.w * (kv.w + (float)e0[i * 4 + 3]);
  }
#pragma unroll
  for (int i = 0; i < 2; ++i) {
    float4 qv = *(const float4*)(qp + 8 + i * 4);
    float4 kv = *(const float4*)(kp + 8 + i * 4);
    sc += qv.x * (kv.x + (float)e1[i * 4 + 0]) + qv.y * (kv.y + (float)e1[i * 4 + 1]) +
          qv.z * (kv.z + (float)e1[i * 4 + 2]) + qv.w * (kv.w + (float)e1[i * 4 + 3]);
  }
  escore[tid] = expf(sc);
}

// ---------------- gather (single pass): z + unnormalized o; inv factors out ----------------
__global__ __launch_bounds__(128)
void k_gather(const int* __restrict__ eids_all, const int* __restrict__ offs,
              const int* __restrict__ src, const float* __restrict__ vmat,
              const bf16_t* __restrict__ emat, const float* __restrict__ escore,
              float* __restrict__ o, float* __restrict__ invz) {
  int nid = blockIdx.x;
  int t = threadIdx.x;          // dim 0..127 ; h = t>>4
  int h = t >> 4;
  int beg = offs[nid], end = offs[nid + 1];
  __shared__ int eids[128];
  __shared__ int srcs[128];
  float z = 0.f, acc = 0.f;
  for (int c0 = beg; c0 < end; c0 += 128) {
    int cnt = min(128, end - c0);
    __syncthreads();
    if (t < cnt) { int e_ = eids_all[c0 + t]; eids[t] = e_; srcs[t] = src[e_]; }
    __syncthreads();
    int j = 0;
    for (; j + 3 < cnt; j += 4) {
      int e0 = eids[j], e1 = eids[j + 1], e2 = eids[j + 2], e3 = eids[j + 3];
      float es0 = escore[(size_t)e0 * H + h];
      float es1 = escore[(size_t)e1 * H + h];
      float es2 = escore[(size_t)e2 * H + h];
      float es3 = escore[(size_t)e3 * H + h];
      float ev0 = (float)emat[(size_t)e0 * D + t];
      float ev1 = (float)emat[(size_t)e1 * D + t];
      float ev2 = (float)emat[(size_t)e2 * D + t];
      float ev3 = (float)emat[(size_t)e3 * D + t];
      float vv0 = vmat[(size_t)srcs[j] * D + t];
      float vv1 = vmat[(size_t)srcs[j + 1] * D + t];
      float vv2 = vmat[(size_t)srcs[j + 2] * D + t];
      float vv3 = vmat[(size_t)srcs[j + 3] * D + t];
      z += (es0 + es1) + (es2 + es3);
      acc += es0 * (vv0 + ev0) + es1 * (vv1 + ev1) +
             es2 * (vv2 + ev2) + es3 * (vv3 + ev3);
    }
    for (; j < cnt; ++j) {
      int e0 = eids[j];
      float es0 = escore[(size_t)e0 * H + h];
      float ev0 = (float)emat[(size_t)e0 * D + t];
      float vv0 = vmat[(size_t)srcs[j] * D + t];
      z += es0;
      acc += es0 * (vv0 + ev0);
    }
  }
  float inv = INV_SQD / (EPS_Z + z);
  o[(size_t)nid * D + t] = acc * inv;
  if ((t & 15) == 0) invz[(size_t)nid * H + h] = inv;
}

// ---------------- norm_escore = escore * invz[dst] ----------------
__global__ __launch_bounds__(256)
void k_ns(const int* __restrict__ dst, const float* __restrict__ escore,
          const float* __restrict__ invz, float* __restrict__ out_ns, int EH) {
  int i = blockIdx.x * 256 + threadIdx.x;
  if (i < EH) {
    int eg = i >> 3, h = i & 7;
    out_ns[i] = escore[i] * invz[(size_t)dst[eg] * H + h];
  }
}

// ---------------- final: gating GEMM (bf16 1-pass) + mix + LN + leaky ----------------
__global__ __launch_bounds__(256)
void k_final(const float* __restrict__ o, const float* __restrict__ r,
             const bf16_t* __restrict__ pkg,   // packed Wg frags, K=384
             const float* __restrict__ bg,
             const float* __restrict__ lng, const float* __restrict__ lnb,
             float* __restrict__ xout, int M) {
  __shared__ __align__(16) char smem[3 * 64 * 128 * 2];   // 48 KB: 3 bf16 segments
  float* e_s = (float*)smem;                               // [64][132] fp32 alias
  const int t = threadIdx.x;
  const int row0 = blockIdx.x * 64;

#pragma unroll
  for (int i = 0; i < 8; ++i) {
    int f = t + i * 256;
    int row = f >> 5, c4 = f & 31;
    float4 ov = make_float4(0.f, 0.f, 0.f, 0.f), rv = ov;
    if (row0 + row < M) {
      ov = *(const float4*)(o + (size_t)(row0 + row) * D + c4 * 4);
      rv = *(const float4*)(r + (size_t)(row0 + row) * D + c4 * 4);
    }
    int off = swzA(row, c4 * 8);
    bf16x4 hv;
    hv[0] = (bf16_t)ov.x; hv[1] = (bf16_t)ov.y; hv[2] = (bf16_t)ov.z; hv[3] = (bf16_t)ov.w;
    *(bf16x4*)(smem + off) = hv;
    hv[0] = (bf16_t)rv.x; hv[1] = (bf16_t)rv.y; hv[2] = (bf16_t)rv.z; hv[3] = (bf16_t)rv.w;
    *(bf16x4*)(smem + 16384 + off) = hv;
    hv[0] = (bf16_t)(ov.x - rv.x); hv[1] = (bf16_t)(ov.y - rv.y);
    hv[2] = (bf16_t)(ov.z - rv.z); hv[3] = (bf16_t)(ov.w - rv.w);
    *(bf16x4*)(smem + 32768 + off) = hv;
  }
  __syncthreads();

  const int lane = t & 63, w = t >> 6;
  const int fr = lane & 15, fg = lane >> 4;
  f32x4 acc[8];
#pragma unroll
  for (int ct = 0; ct < 8; ++ct) acc[ct] = (f32x4){0.f, 0.f, 0.f, 0.f};

#pragma unroll
  for (int s = 0; s < 3; ++s) {
    char* base = smem + s * 16384;
    const bf16x8* Ph = (const bf16x8*)pkg + lane + s * 2048;
#pragma unroll
    for (int kc = 0; kc < 4; ++kc) {
      bf16x8 ah = *(const bf16x8*)(base + swzA(w * 16 + fr, kc * 64 + fg * 16));
      const bf16x8* ph = Ph + kc * 512;
#pragma unroll
      for (int ct = 0; ct < 8; ++ct)
        acc[ct] = __builtin_amdgcn_mfma_f32_16x16x32_bf16(ah, ph[ct * 64], acc[ct], 0, 0, 0);
    }
  }
  __syncthreads();

#pragma unroll
  for (int ct = 0; ct < 8; ++ct) {
    int col = ct * 16 + fr;
    float b = bg[col];
#pragma unroll
    for (int p = 0; p < 4; ++p) {
      int row = w * 16 + fg * 4 + p;
      e_s[row * 132 + col] = acc[ct][p] + b;
    }
  }
  __syncthreads();

#pragma unroll
  for (int i = 0; i < 8; ++i) {
    int f = t + i * 256;
    int row = f >> 5, c4 = f & 31;
    int grow = row0 + row;
    float4 g4 = *(const float4*)&e_s[row * 132 + c4 * 4];
    float4 ov = make_float4(0.f, 0.f, 0.f, 0.f), rv = ov;
    if (grow < M) {
      ov = *(const float4*)(o + (size_t)grow * D + c4 * 4);
      rv = *(const float4*)(r + (size_t)grow * D + c4 * 4);
    }
    float b0 = 1.f / (1.f + expf(-g4.x));
    float b1 = 1.f / (1.f + expf(-g4.y));
    float b2 = 1.f / (1.f + expf(-g4.z));
    float b3 = 1.f / (1.f + expf(-g4.w));
    float h0 = ov.x + b0 * (rv.x - ov.x);
    float h1 = ov.y + b1 * (rv.y - ov.y);
    float h2 = ov.z + b2 * (rv.z - ov.z);
    float h3 = ov.w + b3 * (rv.w - ov.w);
    float s1 = h0 + h1 + h2 + h3;
#pragma unroll
    for (int m = 1; m < 32; m <<= 1) s1 += __shfl_xor(s1, m);
    float mu = s1 * (1.f / 128.f);
    float d0 = h0 - mu, d1 = h1 - mu, d2 = h2 - mu, d3 = h3 - mu;
    float s2 = d0 * d0 + d1 * d1 + d2 * d2 + d3 * d3;
#pragma unroll
    for (int m = 1; m < 32; m <<= 1) s2 += __shfl_xor(s2, m);
    float rsig = rsqrtf(s2 * (1.f / 128.f) + LN_EPS);
    float4 gv  = *(const float4*)(lng + c4 * 4);
    float4 bv2 = *(const float4*)(lnb + c4 * 4);
    float4 res;
    res.x = d0 * rsig * gv.x + bv2.x;
    res.y = d1 * rsig * gv.y + bv2.y;
    res.z = d2 * rsig * gv.z + bv2.z;
    res.w = d3 * rsig * gv.w + bv2.w;
    res.x = res.x >= 0.f ? res.x : NEG * res.x;
    res.y = res.y >= 0.f ? res.y : NEG * res.y;
    res.z = res.z >= 0.f ? res.z : NEG * res.z;
    res.w = res.w >= 0.f ? res.w : NEG * res.w;
    if (grow < M)
      *(float4*)(xout + (size_t)grow * D + c4 * 4) = res;
  }
}

// ---------------- launcher ----------------
extern "C" void kernel_launch(void* const* d_in, const int* in_sizes, int n_in,
                              void* d_out, int out_size, void* d_ws, size_t ws_size,
                              hipStream_t stream) {
  const float* x   = (const float*)d_in[0];
  const float* y   = (const float*)d_in[1];
  const int*   src = (const int*)d_in[2];
  const int*   dst = (const int*)d_in[3];
  const float* Wq = (const float*)d_in[4];  const float* bq = (const float*)d_in[5];
  const float* Wk = (const float*)d_in[6];  const float* bk = (const float*)d_in[7];
  const float* Wv = (const float*)d_in[8];  const float* bv = (const float*)d_in[9];
  const float* We = (const float*)d_in[10]; const float* be = (const float*)d_in[11];
  const float* Wr = (const float*)d_in[12]; const float* br = (const float*)d_in[13];
  const float* Wg = (const float*)d_in[14]; const float* bg = (const float*)d_in[15];
  const float* lng = (const float*)d_in[16]; const float* lnb = (const float*)d_in[17];

  const int N = in_sizes[0] / D;
  const int E = in_sizes[2];

  float* xout   = (float*)d_out;
  float* out_ns = (float*)d_out + (size_t)N * D;

  char* w = (char*)d_ws;
  auto alloc = [&](size_t bytes) -> char* {
    char* p = w;
    w += (bytes + 255) & ~(size_t)255;
    return p;
  };
  float* q  = (float*)alloc((size_t)N * D * 4);
  float* k  = (float*)alloc((size_t)N * D * 4);
  float* v  = (float*)alloc((size_t)N * D * 4);
  float* r  = (float*)alloc((size_t)N * D * 4);
  float* o  = (float*)alloc((size_t)N * D * 4);
  float* escore = (float*)alloc((size_t)E * H * 4);
  float* invz   = (float*)alloc((size_t)N * H * 4);
  int* cnt    = (int*)alloc((size_t)N * 4);
  int* offs   = (int*)alloc((size_t)(N + 1) * 4);
  int* cursor = (int*)alloc((size_t)N * 4);
  int* eids   = (int*)alloc((size_t)E * 4);
  int* bsum   = (int*)alloc(4096);
  bf16_t* pk_hi[6];
  bf16_t* pk_lo[6];
  const float* Ws[6] = {Wq, Wk, Wv, Wr, We, Wg};
  int Ks[6] = {D, D, D, D, D, 3 * D};
  for (int i = 0; i < 6; ++i) {
    pk_hi[i] = (bf16_t*)alloc((size_t)Ks[i] * D * 2);
    pk_lo[i] = (bf16_t*)alloc((size_t)Ks[i] * D * 2);
  }
  bf16_t* e = (bf16_t*)alloc((size_t)E * D * 2);
  if ((size_t)(w - (char*)d_ws) > ws_size) return;

  // pack W fragments
  PackArgs pa;
  for (int i = 0; i < 6; ++i) {
    pa.W[i] = Ws[i]; pa.hi[i] = pk_hi[i]; pa.lo[i] = pk_lo[i]; pa.K[i] = Ks[i];
  }
  k_packw<<<dim3(24, 6), 256, 0, stream>>>(pa);

  // CSR build
  int nb_scan = (N + 255) / 256;
  k_zero_ints<<<256, 256, 0, stream>>>(cnt, N);
  k_zero_ints<<<256, 256, 0, stream>>>(cursor, N);
  k_count<<<(E + 255) / 256, 256, 0, stream>>>(dst, cnt, E);
  k_scan_part<<<nb_scan, 256, 0, stream>>>(cnt, bsum, N);
  k_scan_mid<<<1, 1, 0, stream>>>(bsum, nb_scan);
  k_scan_fin<<<nb_scan, 256, 0, stream>>>(cnt, bsum, offs, N, E);
  k_scatter<<<(E + 255) / 256, 256, 0, stream>>>(dst, offs, cursor, eids, E);

  // node projections q,k,v,r
  int nbn = (N + 63) / 64;
  NP np;
  np.pkh[0] = pk_hi[0]; np.pkl[0] = pk_lo[0]; np.b[0] = bq; np.C[0] = q;
  np.pkh[1] = pk_hi[1]; np.pkl[1] = pk_lo[1]; np.b[1] = bk; np.C[1] = k;
  np.pkh[2] = pk_hi[2]; np.pkl[2] = pk_lo[2]; np.b[2] = bv; np.C[2] = v;
  np.pkh[3] = pk_hi[3]; np.pkl[3] = pk_lo[3]; np.b[3] = br; np.C[3] = r;
  k_nodeproj<<<dim3(nbn, 4), 256, 0, stream>>>(x, np, N);

  // edge projection (pipelined, grid-stride over tiles)
  int ntiles = (E + 63) / 64;
  int nbe = ntiles < 2500 ? ntiles : 2500;
  k_gemm_edge<<<nbe, 256, 0, stream>>>(y, pk_hi[4], pk_lo[4], be, e, E, ntiles);

  // scores
  k_score<<<(E * H + 255) / 256, 256, 0, stream>>>(src, dst, q, k, e, escore, E);

  // single-pass segment softmax + aggregation
  k_gather<<<N, 128, 0, stream>>>(eids, offs, src, v, e, escore, o, invz);

  // norm_escore
  k_ns<<<(E * H + 255) / 256, 256, 0, stream>>>(dst, escore, invz, out_ns, E * H);

  // gating + LayerNorm + leaky ReLU
  k_final<<<nbn, 256, 0, stream>>>(o, r, pk_hi[5], bg, lng, lnb, xout, N);
}